// Round 3
// baseline (889.349 us; speedup 1.0000x reference)
//
#include <hip/hip_runtime.h>
#include <hip/hip_bf16.h>
#include <cstddef>

#define L_SEQ   4096
#define BATCH   32
#define TOFF    1024
#define TBUF    3072
#define NLAYERS 30

typedef __attribute__((ext_vector_type(8))) short short8v;
typedef __attribute__((ext_vector_type(4))) float f32x4;

static const size_t HSZ = (size_t)BATCH * TBUF * 64;

// dynamic LDS layout (48 KB total -> 3 blocks/CU)
#define LDS_B  0        // W1: 128 rows x 128 k bf16, stride 256B, swizzled (32 KB)
#define LDS_Z  32768    // z: 128 rows x 64 ch bf16, stride 128B, swizzled (16 KB)

__device__ inline float fast_sigmoid(float x) {
  x = fminf(fmaxf(x, -30.f), 30.f);
  return __builtin_amdgcn_rcpf(1.f + __expf(-x));
}
__device__ inline float fast_tanh(float x) {
  x = fminf(fmaxf(x, -15.f), 15.f);
  float e = __expf(-2.f * x);
  return (1.f - e) * __builtin_amdgcn_rcpf(1.f + e);
}
__device__ inline unsigned short f2bf(float f) {  // RNE fp32 -> bf16
  unsigned u = __float_as_uint(f);
  unsigned r = u + 0x7FFF + ((u >> 16) & 1);
  return (unsigned short)(r >> 16);
}

// swizzled LDS fragment read: 8 contiguous bf16 at (row, k)
__device__ inline short8v lds_frag(const char* smem, int base, int row, int kk,
                                   int rowstride) {
  int byte = base + row * rowstride + kk * 2;
  byte ^= (row & 7) << 4;
  return *(const short8v*)(smem + byte);
}

// load 8 contiguous fp32 from global, convert to bf16 fragment
__device__ inline short8v load_row8_bf16(const float* __restrict__ p) {
  float4 v0 = ((const float4*)p)[0];
  float4 v1 = ((const float4*)p)[1];
  short8v r;
  r[0] = (short)f2bf(v0.x); r[1] = (short)f2bf(v0.y);
  r[2] = (short)f2bf(v0.z); r[3] = (short)f2bf(v0.w);
  r[4] = (short)f2bf(v1.x); r[5] = (short)f2bf(v1.y);
  r[6] = (short)f2bf(v1.z); r[7] = (short)f2bf(v1.w);
  return r;
}

// ---------------------------------------------------------------------------
// prep: bf16-pack W1 = [30][n=128 (f|g)][k=128 (hprev|hcur)], Wr flat, zero skip
// ---------------------------------------------------------------------------
__global__ __launch_bounds__(256) void prep_kernel(
    const float* __restrict__ dil_w, const float* __restrict__ gate_w,
    const float* __restrict__ res_w,
    unsigned short* __restrict__ W1bf, unsigned short* __restrict__ Wrbf,
    float* __restrict__ skip_last)
{
  int idx = blockIdx.x * 256 + threadIdx.x;
  if (idx < NLAYERS * 128 * 128) {
    int l = idx >> 14, r = idx & 16383, n = r >> 7, k = r & 127;
    const float* src = (n < 64) ? dil_w : gate_w;
    int oc = n & 63;
    float v = src[(((size_t)l * 64 + oc) * 64 + (k & 63)) * 2 + (k >> 6)];
    W1bf[idx] = f2bf(v);
  }
  if (idx < NLAYERS * 64 * 64) Wrbf[idx] = f2bf(res_w[idx]);
  if (idx < BATCH * 64) skip_last[idx] = 0.f;
}

// ---------------------------------------------------------------------------
// input 1x1 conv (fp32): h0[b][t][c], t in [1027, 4096)
// ---------------------------------------------------------------------------
__global__ __launch_bounds__(256) void input_conv_kernel(
    const float* __restrict__ x, const float* __restrict__ w,
    const float* __restrict__ bias, float* __restrict__ h)
{
  int b = blockIdx.y;
  int t = 1027 + blockIdx.x * 256 + threadIdx.x;
  if (t >= L_SEQ) return;
  const float* xp = x + ((size_t)b * L_SEQ + t) * 32;
  float xin[32];
#pragma unroll
  for (int j = 0; j < 8; ++j) {
    float4 v = ((const float4*)xp)[j];
    xin[4*j+0] = v.x; xin[4*j+1] = v.y; xin[4*j+2] = v.z; xin[4*j+3] = v.w;
  }
  float* hp = h + ((size_t)b * TBUF + (t - TOFF)) * 64;
#pragma unroll 2
  for (int oc = 0; oc < 64; ++oc) {
    float a0 = bias[oc], a1 = 0.f;
#pragma unroll
    for (int k = 0; k < 32; k += 2) {
      a0 += w[oc * 32 + k]     * xin[k];
      a1 += w[oc * 32 + k + 1] * xin[k + 1];
    }
    hp[oc] = a0 + a1;
  }
}

// ---------------------------------------------------------------------------
// fused MFMA layer: block = 128 positions x 1 batch, 4 waves (32 pos/wave).
// A-fragments loaded direct from global fp32 h (converted in-register).
// W1 in swizzled LDS (only barrier); Wr in registers; z in wave-private LDS.
// tail block: skip tap at virtual t = L (VALU)
// ---------------------------------------------------------------------------
__global__ __launch_bounds__(256, 3) void layer_kernel(
    const float* __restrict__ hin, float* __restrict__ hout,
    const unsigned short* __restrict__ W1bf, const unsigned short* __restrict__ Wrbf,
    const float* __restrict__ dil_w, const float* __restrict__ gate_w,
    const float* __restrict__ skip_w,
    const float* __restrict__ dil_b, const float* __restrict__ gate_b,
    const float* __restrict__ res_b, const float* __restrict__ skip_b,
    float* __restrict__ skip_last, int layer, int d, int tstart)
{
  extern __shared__ char smem[];
  const int b = blockIdx.y;
  const int tid = threadIdx.x;

  if (blockIdx.x == gridDim.x - 1) {
    // ---- skip tail at t = L: z uses only tap0 at h[L-d] ----
    float* hp = (float*)smem;
    float* zl = hp + 64;
    if (tid < 64)
      hp[tid] = hin[((size_t)b * TBUF + (L_SEQ - d - TOFF)) * 64 + tid];
    __syncthreads();
    if (tid < 64) {
      int dc = tid;
      float f = dil_b[layer * 64 + dc], gg = gate_b[layer * 64 + dc];
      const float* wd = dil_w  + (size_t)(layer * 64 + dc) * 128;
      const float* wg = gate_w + (size_t)(layer * 64 + dc) * 128;
      for (int ic = 0; ic < 64; ++ic) {
        f  += wd[ic * 2] * hp[ic];
        gg += wg[ic * 2] * hp[ic];
      }
      zl[dc] = fast_tanh(f) * fast_sigmoid(gg);
    }
    __syncthreads();
    if (tid < 64) {
      int co = tid;
      float s = skip_b[layer * 64 + co];
      const float* wsk = skip_w + (size_t)(layer * 64 + co) * 64;
      for (int dc = 0; dc < 64; ++dc) s += wsk[dc] * zl[dc];
      skip_last[b * 64 + co] += s;   // race-free: launches serialize layers
    }
    return;
  }

  const int t0 = tstart + blockIdx.x * 128;

  // ---- stage W1 -> LDS [128][128] bf16, swizzled (the only cross-wave dep) ----
  {
    int n = tid >> 1, half = tid & 1;
    const short8v* src =
        (const short8v*)(W1bf + (size_t)layer * 16384 + n * 128 + half * 64);
#pragma unroll
    for (int c = 0; c < 8; ++c) {
      short8v pk = src[c];
      int byte = n * 256 + half * 128 + c * 16;
      byte ^= (n & 7) << 4;
      *(short8v*)(smem + LDS_B + byte) = pk;
    }
  }
  __syncthreads();

  const int lane = tid & 63;
  const int wid  = tid >> 6;
  const int lcol = lane & 15;
  const int lg   = lane >> 4;
  const int wrow = wid * 32;          // wave's 32 position-rows in block
  const float* hb = hin + (size_t)b * TBUF * 64;

  // ---- GEMM1 + activation + z->LDS, per 16-row fragment ----
#pragma unroll
  for (int rf = 0; rf < 2; ++rf) {
    int t = t0 + wrow + rf * 16 + lcol;
    if (t >= L_SEQ) t = L_SEQ - 1;           // clamp; rows discarded at write
    short8v a[4];
#pragma unroll
    for (int s = 0; s < 4; ++s) {            // s<2: hprev (tap0), s>=2: hcur
      int tsrc = (s < 2) ? (t - d) : t;
      int ch = (s & 1) * 32 + lg * 8;
      a[s] = load_row8_bf16(hb + (size_t)(tsrc - TOFF) * 64 + ch);
    }
    f32x4 cf[8];
#pragma unroll
    for (int j = 0; j < 8; ++j) {
      int n = j * 16 + lcol;
      float bias = (n < 64) ? dil_b[layer * 64 + n] : gate_b[layer * 64 + n - 64];
      cf[j] = (f32x4){bias, bias, bias, bias};
    }
#pragma unroll
    for (int s = 0; s < 4; ++s) {
#pragma unroll
      for (int j = 0; j < 8; ++j) {
        short8v bb = lds_frag(smem, LDS_B, j * 16 + lcol, s * 32 + lg * 8, 256);
        cf[j] = __builtin_amdgcn_mfma_f32_16x16x32_bf16(a[s], bb, cf[j], 0, 0, 0);
      }
    }
#pragma unroll
    for (int j = 0; j < 4; ++j) {
#pragma unroll
      for (int r = 0; r < 4; ++r) {
        float z = fast_tanh(cf[j][r]) * fast_sigmoid(cf[j + 4][r]);
        int row = wrow + rf * 16 + lg * 4 + r;   // C layout: row=(lane>>4)*4+reg
        int byte = row * 128 + (j * 16 + lcol) * 2;
        byte ^= (row & 7) << 4;
        *(unsigned short*)(smem + LDS_Z + byte) = f2bf(z);
      }
    }
  }
  __syncthreads();   // cheap safety barrier before z reads

  // ---- Wr fragments in registers (global, L2-hot) ----
  short8v wr[4][2];
  const unsigned short* wrp = Wrbf + (size_t)layer * 4096;
#pragma unroll
  for (int j2 = 0; j2 < 4; ++j2)
#pragma unroll
    for (int s2 = 0; s2 < 2; ++s2)
      wr[j2][s2] = *(const short8v*)(wrp + (j2 * 16 + lcol) * 64 + s2 * 32 + lg * 8);

  // ---- GEMM2 + fp32 residual epilogue ----
#pragma unroll
  for (int rf = 0; rf < 2; ++rf) {
    f32x4 c2[4];
#pragma unroll
    for (int j2 = 0; j2 < 4; ++j2) {
      float bias = res_b[layer * 64 + j2 * 16 + lcol];
      c2[j2] = (f32x4){bias, bias, bias, bias};
    }
#pragma unroll
    for (int s2 = 0; s2 < 2; ++s2) {
      short8v a2 = lds_frag(smem, LDS_Z, wrow + rf * 16 + lcol,
                            s2 * 32 + lg * 8, 128);
#pragma unroll
      for (int j2 = 0; j2 < 4; ++j2)
        c2[j2] = __builtin_amdgcn_mfma_f32_16x16x32_bf16(a2, wr[j2][s2], c2[j2], 0, 0, 0);
    }
#pragma unroll
    for (int j2 = 0; j2 < 4; ++j2) {
      int col = j2 * 16 + lcol;
#pragma unroll
      for (int r = 0; r < 4; ++r) {
        int t = t0 + wrow + rf * 16 + lg * 4 + r;
        if (t < L_SEQ) {
          size_t idx = ((size_t)b * TBUF + t - TOFF) * 64 + col;
          hout[idx] = hin[idx] + c2[j2][r];
        }
      }
    }
  }
}

// ---------------------------------------------------------------------------
// epilogue: relu -> end1 (64->128) -> relu -> mean/lv heads -> vol
// 256 threads: (b = tid&31, eg = tid>>5); LDS reduce over 8 e-groups
// ---------------------------------------------------------------------------
__global__ __launch_bounds__(256) void final_kernel(
    const float* __restrict__ skip_last,
    const float* __restrict__ e1w, const float* __restrict__ e1b,
    const float* __restrict__ mw,  const float* __restrict__ mb,
    const float* __restrict__ lw,  const float* __restrict__ lb,
    float* __restrict__ out)
{
  __shared__ float rm[8][32], rl[8][32];
  int b  = threadIdx.x & 31;
  int eg = threadIdx.x >> 5;
  float y1[64];
  const float4* yp = (const float4*)(skip_last + b * 64);
#pragma unroll
  for (int q = 0; q < 16; ++q) {
    float4 v = yp[q];
    y1[4*q+0] = fmaxf(v.x, 0.f); y1[4*q+1] = fmaxf(v.y, 0.f);
    y1[4*q+2] = fmaxf(v.z, 0.f); y1[4*q+3] = fmaxf(v.w, 0.f);
  }
  float mp = 0.f, lp = 0.f;
  for (int ei = 0; ei < 16; ++ei) {
    int e = eg * 16 + ei;
    const float4* wp = (const float4*)(e1w + e * 64);
    float a0 = e1b[e], a1 = 0.f;
#pragma unroll
    for (int q = 0; q < 16; ++q) {
      float4 w4 = wp[q];
      a0 += w4.x * y1[4*q+0] + w4.z * y1[4*q+2];
      a1 += w4.y * y1[4*q+1] + w4.w * y1[4*q+3];
    }
    float a = fmaxf(a0 + a1, 0.f);
    mp += mw[e] * a;
    lp += lw[e] * a;
  }
  rm[eg][b] = mp; rl[eg][b] = lp;
  __syncthreads();
  if (threadIdx.x < 32) {
    int bb = threadIdx.x;
    float m = mb[0], l = lb[0];
#pragma unroll
    for (int g = 0; g < 8; ++g) { m += rm[g][bb]; l += rl[g][bb]; }
    out[bb]      = m;
    out[32 + bb] = l;
    out[64 + bb] = expf(0.5f * l);
  }
}

// ---------------------------------------------------------------------------
extern "C" void kernel_launch(void* const* d_in, const int* in_sizes, int n_in,
                              void* d_out, int out_size, void* d_ws, size_t ws_size,
                              hipStream_t stream)
{
  const float* x       = (const float*)d_in[0];
  const float* input_w = (const float*)d_in[1];
  const float* input_b = (const float*)d_in[2];
  const float* dil_w   = (const float*)d_in[3];
  const float* dil_b   = (const float*)d_in[4];
  const float* gate_w  = (const float*)d_in[5];
  const float* gate_b  = (const float*)d_in[6];
  const float* skip_w  = (const float*)d_in[7];
  const float* skip_b  = (const float*)d_in[8];
  const float* res_w   = (const float*)d_in[9];
  const float* res_b   = (const float*)d_in[10];
  const float* e1w     = (const float*)d_in[11];
  const float* e1b     = (const float*)d_in[12];
  const float* mw      = (const float*)d_in[13];
  const float* mb      = (const float*)d_in[14];
  const float* lw      = (const float*)d_in[15];
  const float* lb      = (const float*)d_in[16];

  float* ws        = (float*)d_ws;
  float* hA        = ws;
  float* hB        = hA + HSZ;
  float* skip_last = hB + HSZ;
  unsigned short* W1bf = (unsigned short*)(skip_last + BATCH * 64);
  unsigned short* Wrbf = W1bf + (size_t)NLAYERS * 128 * 128;

  int dil[NLAYERS];
  int R[NLAYERS + 1];
  for (int blk = 0; blk < 3; ++blk)
    for (int l = 0; l < 10; ++l) dil[blk * 10 + l] = 1 << l;
  R[NLAYERS] = L_SEQ;
  for (int i = NLAYERS - 1; i >= 0; --i) R[i] = R[i + 1] - dil[i];
  // R[0] == 1027

  prep_kernel<<<(NLAYERS * 128 * 128 + 255) / 256, 256, 0, stream>>>(
      dil_w, gate_w, res_w, W1bf, Wrbf, skip_last);

  {
    int nt = L_SEQ - R[0];  // 3069
    dim3 g((nt + 255) / 256, BATCH);
    input_conv_kernel<<<g, 256, 0, stream>>>(x, input_w, input_b, hA);
  }

  float* hin  = hA;
  float* hout = hB;
  for (int i = 0; i < NLAYERS; ++i) {
    int nt = L_SEQ - R[i + 1];            // normal positions (0 for last layer)
    int nblk = (nt + 127) / 128;
    dim3 g(nblk + 1, BATCH);              // +1 tail block for skip @ t=L
    layer_kernel<<<g, 256, 49152, stream>>>(
        hin, hout, W1bf, Wrbf,
        dil_w, gate_w, skip_w,
        dil_b, gate_b, res_b, skip_b,
        skip_last, i, dil[i], R[i + 1]);
    float* tmp = hin; hin = hout; hout = tmp;
  }

  final_kernel<<<1, 256, 0, stream>>>(skip_last, e1w, e1b, mw, mb, lw, lb,
                                      (float*)d_out);
}

// Round 6
// 792.041 us; speedup vs baseline: 1.1229x; 1.1229x over previous
//
#include <hip/hip_runtime.h>
#include <hip/hip_bf16.h>
#include <hip/hip_cooperative_groups.h>
#include <cstddef>

namespace cg = cooperative_groups;

#define L_SEQ   4096
#define BATCH   32
#define TOFF    1024
#define TBUF    3072
#define NLAYERS 30
#define TT      192           // mega: positions per block tile
#define NT      16            // mega: tiles; 16*192 = 3072

typedef __attribute__((ext_vector_type(8))) short short8v;
typedef __attribute__((ext_vector_type(4))) float f32x4;

static const size_t HSZ = (size_t)BATCH * TBUF * 64;

// ---- mega-kernel LDS layout (65536 B dynamic) ----
#define MG_H  0         // h bf16 [192][64] stride 128B, swizzled (24576 B)
#define MG_B  24576     // W1 bf16 [128][128] stride 256B, swizzled (32768 B); x-tile during init
#define MG_Z  57344     // z slots 4 waves x 16 rows x 128B (8192 B); Wi during init; ztap overlays [0,256)

// ---- fallback layer-kernel LDS layout (65536 B dynamic) ----
#define FB_A  0         // A 64x128 bf16 stride 256B (16 KB)
#define FB_B  16384     // W1 128x128 bf16 stride 256B (32 KB)
#define FB_Z  49152     // z 64x64 bf16 stride 128B (8 KB)
#define FB_W  57344     // Wr 64x64 bf16 stride 128B (8 KB)

__device__ inline float fast_sigmoid(float x) {
  x = fminf(fmaxf(x, -30.f), 30.f);
  return __builtin_amdgcn_rcpf(1.f + __expf(-x));
}
__device__ inline float fast_tanh(float x) {
  x = fminf(fmaxf(x, -15.f), 15.f);
  float e = __expf(-2.f * x);
  return (1.f - e) * __builtin_amdgcn_rcpf(1.f + e);
}
__device__ inline unsigned short f2bf(float f) {  // RNE fp32 -> bf16
  unsigned u = __float_as_uint(f);
  unsigned r = u + 0x7FFF + ((u >> 16) & 1);
  return (unsigned short)(r >> 16);
}
__device__ inline float bf2f(unsigned short u) {
  return __uint_as_float((unsigned)u << 16);
}
__device__ inline short8v lds_frag(const char* smem, int base, int row, int kk,
                                   int rowstride) {
  int byte = base + row * rowstride + kk * 2;
  byte ^= (row & 7) << 4;
  return *(const short8v*)(smem + byte);
}
__device__ inline short8v load_row8_bf16(const float* __restrict__ p) {
  float4 v0 = ((const float4*)p)[0];
  float4 v1 = ((const float4*)p)[1];
  short8v r;
  r[0] = (short)f2bf(v0.x); r[1] = (short)f2bf(v0.y);
  r[2] = (short)f2bf(v0.z); r[3] = (short)f2bf(v0.w);
  r[4] = (short)f2bf(v1.x); r[5] = (short)f2bf(v1.y);
  r[6] = (short)f2bf(v1.z); r[7] = (short)f2bf(v1.w);
  return r;
}

// ===========================================================================
// MEGA (cooperative) kernel
// ===========================================================================
__global__ __launch_bounds__(256) void wavenet_mega(
    const float* __restrict__ x,
    const float* __restrict__ input_w, const float* __restrict__ input_b,
    const float* __restrict__ dil_w,  const float* __restrict__ dil_b,
    const float* __restrict__ gate_w, const float* __restrict__ gate_b,
    const float* __restrict__ skip_w, const float* __restrict__ skip_b,
    const float* __restrict__ res_w,  const float* __restrict__ res_b,
    const float* __restrict__ e1w, const float* __restrict__ e1b,
    const float* __restrict__ mw, const float* __restrict__ mb,
    const float* __restrict__ lw, const float* __restrict__ lb,
    unsigned short* __restrict__ Hg, float* __restrict__ skip_last,
    unsigned short* __restrict__ W1bf, unsigned short* __restrict__ Wrbf,
    float* __restrict__ out)
{
  extern __shared__ char smem[];
  float* ztap = (float*)(smem + MG_Z);   // 256 B overlay (wave-0 slots only)
  cg::grid_group grid = cg::this_grid();

  const int tid = threadIdx.x;
  const int tt  = blockIdx.x;
  const int b   = blockIdx.y;
  const int t0c = tt * TT;
  const int t0  = 1024 + t0c;
  const int lane = tid & 63, wv = tid >> 6;
  const int lcol = lane & 15, lg = lane >> 4;
  unsigned short* HgB = Hg + (size_t)b * 3072 * 64;

  // phase 0: pack weights
  {
    const int gtid = (b * NT + tt) * 256 + tid;
    for (int idx = gtid; idx < NLAYERS * 128 * 128; idx += NT * BATCH * 256) {
      int l = idx >> 14, r = idx & 16383, n = r >> 7, k = r & 127;
      const float* src = (n < 64) ? dil_w : gate_w;
      W1bf[idx] = f2bf(src[(((size_t)l * 64 + (n & 63)) * 64 + (k & 63)) * 2 + (k >> 6)]);
    }
    for (int idx = gtid; idx < NLAYERS * 64 * 64; idx += NT * BATCH * 256)
      Wrbf[idx] = f2bf(res_w[idx]);
    if (tt == 0 && tid < 64) skip_last[b * 64 + tid] = 0.f;
  }

  // phase 1: input conv via MFMA (K=32)
  {
    {
      const float4* s4 = (const float4*)(input_w + tid * 8);
      float4 a4 = s4[0], b4 = s4[1];
      short8v pk;
      pk[0]=(short)f2bf(a4.x); pk[1]=(short)f2bf(a4.y); pk[2]=(short)f2bf(a4.z); pk[3]=(short)f2bf(a4.w);
      pk[4]=(short)f2bf(b4.x); pk[5]=(short)f2bf(b4.y); pk[6]=(short)f2bf(b4.z); pk[7]=(short)f2bf(b4.w);
      *(short8v*)(smem + MG_Z + tid * 16) = pk;
    }
    if (tid < TT) {
      const float4* src = (const float4*)(x + ((size_t)b * L_SEQ + t0 + tid) * 32);
#pragma unroll
      for (int c = 0; c < 4; ++c) {
        float4 a4 = src[c * 2], b4 = src[c * 2 + 1];
        short8v pk;
        pk[0]=(short)f2bf(a4.x); pk[1]=(short)f2bf(a4.y); pk[2]=(short)f2bf(a4.z); pk[3]=(short)f2bf(a4.w);
        pk[4]=(short)f2bf(b4.x); pk[5]=(short)f2bf(b4.y); pk[6]=(short)f2bf(b4.z); pk[7]=(short)f2bf(b4.w);
        *(short8v*)(smem + MG_B + ((tid * 128 + c * 16) ^ ((tid & 7) << 4))) = pk;
      }
    }
  }
  __syncthreads();

  f32x4 hreg[3][4];
#pragma unroll
  for (int rf = 0; rf < 3; ++rf) {
    int row = wv * 48 + rf * 16 + lcol;
    short8v ax = *(const short8v*)(smem + MG_B + ((row * 128 + lg * 16) ^ ((row & 7) << 4)));
#pragma unroll
    for (int j = 0; j < 4; ++j) {
      float bias = input_b[j * 16 + lcol];
      f32x4 c0 = {bias, bias, bias, bias};
      short8v bw = *(const short8v*)(smem + MG_Z + (j * 16 + lcol) * 64 + lg * 16);
      hreg[rf][j] = __builtin_amdgcn_mfma_f32_16x16x32_bf16(ax, bw, c0, 0, 0, 0);
    }
  }
  __syncthreads();

#pragma unroll
  for (int rf = 0; rf < 3; ++rf)
#pragma unroll
    for (int j = 0; j < 4; ++j)
#pragma unroll
      for (int r = 0; r < 4; ++r) {
        int row = wv * 48 + rf * 16 + lg * 4 + r;
        int byte = (row * 128 + (j * 16 + lcol) * 2) ^ ((row & 7) << 4);
        *(unsigned short*)(smem + MG_H + byte) = f2bf(hreg[rf][j][r]);
      }
  __syncthreads();
  if (tid < 1) {
    int row = TT - 1;
    unsigned short* dst = HgB + (size_t)(t0c + row) * 64;
#pragma unroll
    for (int c = 0; c < 8; ++c) {
      short8v v = *(const short8v*)(smem + MG_H + ((row * 128 + c * 16) ^ ((row & 7) << 4)));
      *(short8v*)(dst + c * 8) = v;
    }
  }
  grid.sync();

  // phase 2: 30 layers
  int Rcur = 1027;
#pragma unroll 1
  for (int i = 0; i < NLAYERS; ++i) {
    const int d = 1 << (i % 10);
    const int R_next = Rcur + d;
    const bool active = (t0 + TT - 1) >= R_next;
    const bool tapown = (tt == (3072 - d) / TT);

    if (active) {
      int n = tid >> 1, half = tid & 1;
      const short8v* src = (const short8v*)(W1bf + (size_t)i * 16384 + n * 128 + half * 64);
#pragma unroll
      for (int c = 0; c < 8; ++c) {
        short8v pk = src[c];
        int byte = (n * 256 + half * 128 + c * 16) ^ ((n & 7) << 4);
        *(short8v*)(smem + MG_B + byte) = pk;
      }
    }
    if (tapown && tid < 64) {
      int rtap = (3072 - d) - t0c;
      float f = dil_b[i * 64 + tid], g = gate_b[i * 64 + tid];
      const float* wd = dil_w  + ((size_t)i * 64 + tid) * 128;
      const float* wg = gate_w + ((size_t)i * 64 + tid) * 128;
      for (int ic = 0; ic < 64; ++ic) {
        float hv = bf2f(*(const unsigned short*)(smem + MG_H +
                        ((rtap * 128 + ic * 2) ^ ((rtap & 7) << 4))));
        f += wd[ic * 2] * hv;
        g += wg[ic * 2] * hv;
      }
      ztap[tid] = fast_tanh(f) * fast_sigmoid(g);
    }
    __syncthreads();
    if (tapown && tid < 64) {
      float s = skip_b[i * 64 + tid];
      const float* wsk = skip_w + ((size_t)i * 64 + tid) * 64;
      float zv[64];
#pragma unroll
      for (int dc = 0; dc < 64; ++dc) zv[dc] = ztap[dc];
      for (int dc = 0; dc < 64; ++dc) s += wsk[dc] * zv[dc];
      skip_last[b * 64 + tid] += s;
    }
    if (active) {
      short8v wr[4][2];
      const unsigned short* wrp = Wrbf + (size_t)i * 4096;
#pragma unroll
      for (int j2 = 0; j2 < 4; ++j2)
#pragma unroll
        for (int s2 = 0; s2 < 2; ++s2)
          wr[j2][s2] = *(const short8v*)(wrp + (j2 * 16 + lcol) * 64 + s2 * 32 + lg * 8);

#pragma unroll
      for (int rf = 0; rf < 3; ++rf) {
        int arow = wv * 48 + rf * 16 + lcol;
        short8v a[4];
#pragma unroll
        for (int s = 0; s < 4; ++s) {
          int ch = (s & 1) * 32 + lg * 8;
          int srcr = arow - ((s < 2) ? d : 0);
          if (srcr >= 0) {
            a[s] = *(const short8v*)(smem + MG_H +
                     ((srcr * 128 + ch * 2) ^ ((srcr & 7) << 4)));
          } else {
            int rg = t0c + srcr; if (rg < 0) rg = 0;
            a[s] = *(const short8v*)(HgB + (size_t)rg * 64 + ch);
          }
        }
        f32x4 cf[8];
#pragma unroll
        for (int j = 0; j < 8; ++j) {
          int n = j * 16 + lcol;
          float bias = (n < 64) ? dil_b[i * 64 + n] : gate_b[i * 64 + n - 64];
          cf[j] = (f32x4){bias, bias, bias, bias};
        }
#pragma unroll
        for (int s = 0; s < 4; ++s)
#pragma unroll
          for (int j = 0; j < 8; ++j) {
            int byte = ((j * 16 + lcol) * 256 + (s * 32 + lg * 8) * 2) ^
                       (((j * 16 + lcol) & 7) << 4);
            short8v bb = *(const short8v*)(smem + MG_B + byte);
            cf[j] = __builtin_amdgcn_mfma_f32_16x16x32_bf16(a[s], bb, cf[j], 0, 0, 0);
          }
#pragma unroll
        for (int j = 0; j < 4; ++j)
#pragma unroll
          for (int r = 0; r < 4; ++r) {
            float z = fast_tanh(cf[j][r]) * fast_sigmoid(cf[j + 4][r]);
            int slot = wv * 16 + lg * 4 + r;
            int byte = (slot * 128 + (j * 16 + lcol) * 2) ^ ((slot & 7) << 4);
            *(unsigned short*)(smem + MG_Z + byte) = f2bf(z);
          }
        f32x4 c2[4];
#pragma unroll
        for (int j2 = 0; j2 < 4; ++j2) {
          float bias = res_b[i * 64 + j2 * 16 + lcol];
          c2[j2] = (f32x4){bias, bias, bias, bias};
        }
#pragma unroll
        for (int s2 = 0; s2 < 2; ++s2) {
          int slot = wv * 16 + lcol;
          short8v a2 = *(const short8v*)(smem + MG_Z +
                         ((slot * 128 + (s2 * 32 + lg * 8) * 2) ^ ((slot & 7) << 4)));
#pragma unroll
          for (int j2 = 0; j2 < 4; ++j2)
            c2[j2] = __builtin_amdgcn_mfma_f32_16x16x32_bf16(a2, wr[j2][s2], c2[j2], 0, 0, 0);
        }
#pragma unroll
        for (int j2 = 0; j2 < 4; ++j2)
#pragma unroll
          for (int r = 0; r < 4; ++r) {
            int trow = t0 + wv * 48 + rf * 16 + lg * 4 + r;
            if (trow >= R_next) hreg[rf][j2][r] += c2[j2][r];
          }
      }
    }
    __syncthreads();
    if (active) {
#pragma unroll
      for (int rf = 0; rf < 3; ++rf)
#pragma unroll
        for (int j = 0; j < 4; ++j)
#pragma unroll
          for (int r = 0; r < 4; ++r) {
            int row = wv * 48 + rf * 16 + lg * 4 + r;
            int byte = (row * 128 + (j * 16 + lcol) * 2) ^ ((row & 7) << 4);
            *(unsigned short*)(smem + MG_H + byte) = f2bf(hreg[rf][j][r]);
          }
    }
    __syncthreads();
    int p = (i < NLAYERS - 1) ? (1 << ((i + 1) % 10)) : 0;
    if (p > TT) p = TT;
    if (tid < p) {
      int row = TT - p + tid;
      unsigned short* dst = HgB + (size_t)(t0c + row) * 64;
#pragma unroll
      for (int c = 0; c < 8; ++c) {
        short8v v = *(const short8v*)(smem + MG_H +
                      ((row * 128 + c * 16) ^ ((row & 7) << 4)));
        *(short8v*)(dst + c * 8) = v;
      }
    }
    grid.sync();
    Rcur = R_next;
  }

  // phase 3: final head
  if (tt == 0) {
    float* red = (float*)smem;
    float mp = 0.f, lp = 0.f;
    if (tid < 128) {
      int e = tid;
      float a = e1b[e];
      const float4* wp = (const float4*)(e1w + e * 64);
      const float4* yp = (const float4*)(skip_last + b * 64);
#pragma unroll
      for (int q = 0; q < 16; ++q) {
        float4 w4 = wp[q], y4 = yp[q];
        a += w4.x * fmaxf(y4.x, 0.f) + w4.y * fmaxf(y4.y, 0.f) +
             w4.z * fmaxf(y4.z, 0.f) + w4.w * fmaxf(y4.w, 0.f);
      }
      a = fmaxf(a, 0.f);
      mp = mw[e] * a;
      lp = lw[e] * a;
    }
    __syncthreads();
    red[tid] = mp;
    red[256 + tid] = lp;
    __syncthreads();
    if (tid == 0) {
      float m = mb[0], l = lb[0];
      for (int k = 0; k < 128; ++k) { m += red[k]; l += red[256 + k]; }
      out[b]      = m;
      out[32 + b] = l;
      out[64 + b] = expf(0.5f * l);
    }
  }
}

// ===========================================================================
// FALLBACK kernels (round-2 proven, 829 us) + parallel final
// ===========================================================================
__global__ __launch_bounds__(256) void prep_kernel(
    const float* __restrict__ dil_w, const float* __restrict__ gate_w,
    const float* __restrict__ res_w,
    unsigned short* __restrict__ W1bf, unsigned short* __restrict__ Wrbf,
    float* __restrict__ skip_last)
{
  int idx = blockIdx.x * 256 + threadIdx.x;
  if (idx < NLAYERS * 128 * 128) {
    int l = idx >> 14, r = idx & 16383, n = r >> 7, k = r & 127;
    const float* src = (n < 64) ? dil_w : gate_w;
    int oc = n & 63;
    float v = src[(((size_t)l * 64 + oc) * 64 + (k & 63)) * 2 + (k >> 6)];
    W1bf[idx] = f2bf(v);
  }
  if (idx < NLAYERS * 64 * 64) Wrbf[idx] = f2bf(res_w[idx]);
  if (idx < BATCH * 64) skip_last[idx] = 0.f;
}

__global__ __launch_bounds__(256) void input_conv_kernel(
    const float* __restrict__ x, const float* __restrict__ w,
    const float* __restrict__ bias, float* __restrict__ h)
{
  int b = blockIdx.y;
  int t = 1027 + blockIdx.x * 256 + threadIdx.x;
  if (t >= L_SEQ) return;
  const float* xp = x + ((size_t)b * L_SEQ + t) * 32;
  float xin[32];
#pragma unroll
  for (int j = 0; j < 8; ++j) {
    float4 v = ((const float4*)xp)[j];
    xin[4*j+0] = v.x; xin[4*j+1] = v.y; xin[4*j+2] = v.z; xin[4*j+3] = v.w;
  }
  float* hp = h + ((size_t)b * TBUF + (t - TOFF)) * 64;
#pragma unroll 2
  for (int oc = 0; oc < 64; ++oc) {
    float a0 = bias[oc], a1 = 0.f;
#pragma unroll
    for (int k = 0; k < 32; k += 2) {
      a0 += w[oc * 32 + k]     * xin[k];
      a1 += w[oc * 32 + k + 1] * xin[k + 1];
    }
    hp[oc] = a0 + a1;
  }
}

__global__ __launch_bounds__(256, 2) void layer_kernel(
    const float* __restrict__ hin, float* __restrict__ hout,
    const unsigned short* __restrict__ W1bf, const unsigned short* __restrict__ Wrbf,
    const float* __restrict__ dil_w, const float* __restrict__ gate_w,
    const float* __restrict__ skip_w,
    const float* __restrict__ dil_b, const float* __restrict__ gate_b,
    const float* __restrict__ res_b, const float* __restrict__ skip_b,
    float* __restrict__ skip_last, int layer, int d, int tstart)
{
  extern __shared__ char smem[];
  const int b = blockIdx.y;
  const int tid = threadIdx.x;

  if (blockIdx.x == gridDim.x - 1) {
    float* hp = (float*)smem;
    float* zl = hp + 64;
    if (tid < 64)
      hp[tid] = hin[((size_t)b * TBUF + (L_SEQ - d - TOFF)) * 64 + tid];
    __syncthreads();
    if (tid < 64) {
      int dc = tid;
      float f = dil_b[layer * 64 + dc], gg = gate_b[layer * 64 + dc];
      const float* wd = dil_w  + (size_t)(layer * 64 + dc) * 128;
      const float* wg = gate_w + (size_t)(layer * 64 + dc) * 128;
      for (int ic = 0; ic < 64; ++ic) {
        f  += wd[ic * 2] * hp[ic];
        gg += wg[ic * 2] * hp[ic];
      }
      zl[dc] = fast_tanh(f) * fast_sigmoid(gg);
    }
    __syncthreads();
    if (tid < 64) {
      int co = tid;
      float s = skip_b[layer * 64 + co];
      const float* wsk = skip_w + (size_t)(layer * 64 + co) * 64;
      for (int dc = 0; dc < 64; ++dc) s += wsk[dc] * zl[dc];
      skip_last[b * 64 + co] += s;
    }
    return;
  }

  const int t0 = tstart + blockIdx.x * 64;

  {
    int row = tid >> 2, part = tid & 3;
    int t = t0 + row; if (t >= L_SEQ) t = L_SEQ - 1;
    int tsrc = (part < 2) ? (t - d) : t;
    const float* src = hin + ((size_t)b * TBUF + (tsrc - TOFF)) * 64 + (part & 1) * 32;
    float v[32];
#pragma unroll
    for (int q = 0; q < 8; ++q) {
      float4 f4 = ((const float4*)src)[q];
      v[4*q] = f4.x; v[4*q+1] = f4.y; v[4*q+2] = f4.z; v[4*q+3] = f4.w;
    }
#pragma unroll
    for (int c = 0; c < 4; ++c) {
      short8v pk;
#pragma unroll
      for (int e = 0; e < 8; ++e) pk[e] = (short)f2bf(v[c * 8 + e]);
      int byte = row * 256 + part * 64 + c * 16;
      byte ^= (row & 7) << 4;
      *(short8v*)(smem + FB_A + byte) = pk;
    }
  }
  {
    int n = tid >> 1, half = tid & 1;
    const short8v* src =
        (const short8v*)(W1bf + (size_t)layer * 16384 + n * 128 + half * 64);
#pragma unroll
    for (int c = 0; c < 8; ++c) {
      short8v pk = src[c];
      int byte = n * 256 + half * 128 + c * 16;
      byte ^= (n & 7) << 4;
      *(short8v*)(smem + FB_B + byte) = pk;
    }
  }
  {
    int co = tid >> 2, q = tid & 3;
    const short8v* src =
        (const short8v*)(Wrbf + (size_t)layer * 4096 + co * 64 + q * 16);
#pragma unroll
    for (int c = 0; c < 2; ++c) {
      short8v pk = src[c];
      int byte = co * 128 + q * 32 + c * 16;
      byte ^= (co & 7) << 4;
      *(short8v*)(smem + FB_W + byte) = pk;
    }
  }
  __syncthreads();

  const int lane = tid & 63;
  const int wid  = tid >> 6;
  const int r0   = wid * 16;
  const int lcol = lane & 15;
  const int lg   = lane >> 4;

  f32x4 cf[8];
#pragma unroll
  for (int j = 0; j < 8; ++j) {
    int n = j * 16 + lcol;
    float bias = (n < 64) ? dil_b[layer * 64 + n] : gate_b[layer * 64 + n - 64];
    cf[j] = (f32x4){bias, bias, bias, bias};
  }
#pragma unroll
  for (int s = 0; s < 4; ++s) {
    short8v a = lds_frag(smem, FB_A, r0 + lcol, s * 32 + lg * 8, 256);
#pragma unroll
    for (int j = 0; j < 8; ++j) {
      short8v bb = lds_frag(smem, FB_B, j * 16 + lcol, s * 32 + lg * 8, 256);
      cf[j] = __builtin_amdgcn_mfma_f32_16x16x32_bf16(a, bb, cf[j], 0, 0, 0);
    }
  }

#pragma unroll
  for (int j = 0; j < 4; ++j) {
#pragma unroll
    for (int r = 0; r < 4; ++r) {
      float z = fast_tanh(cf[j][r]) * fast_sigmoid(cf[j + 4][r]);
      int row = r0 + lg * 4 + r;
      int col = j * 16 + lcol;
      int byte = row * 128 + col * 2;
      byte ^= (row & 7) << 4;
      *(unsigned short*)(smem + FB_Z + byte) = f2bf(z);
    }
  }

  f32x4 c2[4];
#pragma unroll
  for (int j = 0; j < 4; ++j) {
    float bias = res_b[layer * 64 + j * 16 + lcol];
    c2[j] = (f32x4){bias, bias, bias, bias};
  }
#pragma unroll
  for (int s = 0; s < 2; ++s) {
    short8v a2 = lds_frag(smem, FB_Z, r0 + lcol, s * 32 + lg * 8, 128);
#pragma unroll
    for (int j = 0; j < 4; ++j) {
      short8v b2 = lds_frag(smem, FB_W, j * 16 + lcol, s * 32 + lg * 8, 128);
      c2[j] = __builtin_amdgcn_mfma_f32_16x16x32_bf16(a2, b2, c2[j], 0, 0, 0);
    }
  }

#pragma unroll
  for (int j = 0; j < 4; ++j) {
    int col = j * 16 + lcol;
#pragma unroll
    for (int r = 0; r < 4; ++r) {
      int row = r0 + lg * 4 + r;
      int t = t0 + row;
      if (t < L_SEQ) {
        size_t idx = ((size_t)b * TBUF + t - TOFF) * 64 + col;
        hout[idx] = hin[idx] + c2[j][r];
      }
    }
  }
}

__global__ __launch_bounds__(256) void final_kernel(
    const float* __restrict__ skip_last,
    const float* __restrict__ e1w, const float* __restrict__ e1b,
    const float* __restrict__ mw,  const float* __restrict__ mb,
    const float* __restrict__ lw,  const float* __restrict__ lb,
    float* __restrict__ out)
{
  __shared__ float rm[8][32], rl[8][32];
  int b  = threadIdx.x & 31;
  int eg = threadIdx.x >> 5;
  float y1[64];
  const float4* yp = (const float4*)(skip_last + b * 64);
#pragma unroll
  for (int q = 0; q < 16; ++q) {
    float4 v = yp[q];
    y1[4*q+0] = fmaxf(v.x, 0.f); y1[4*q+1] = fmaxf(v.y, 0.f);
    y1[4*q+2] = fmaxf(v.z, 0.f); y1[4*q+3] = fmaxf(v.w, 0.f);
  }
  float mp = 0.f, lp = 0.f;
  for (int ei = 0; ei < 16; ++ei) {
    int e = eg * 16 + ei;
    const float4* wp = (const float4*)(e1w + e * 64);
    float a0 = e1b[e], a1 = 0.f;
#pragma unroll
    for (int q = 0; q < 16; ++q) {
      float4 w4 = wp[q];
      a0 += w4.x * y1[4*q+0] + w4.z * y1[4*q+2];
      a1 += w4.y * y1[4*q+1] + w4.w * y1[4*q+3];
    }
    float a = fmaxf(a0 + a1, 0.f);
    mp += mw[e] * a;
    lp += lw[e] * a;
  }
  rm[eg][b] = mp; rl[eg][b] = lp;
  __syncthreads();
  if (threadIdx.x < 32) {
    int bb = threadIdx.x;
    float m = mb[0], l = lb[0];
#pragma unroll
    for (int g = 0; g < 8; ++g) { m += rm[g][bb]; l += rl[g][bb]; }
    out[bb]      = m;
    out[32 + bb] = l;
    out[64 + bb] = expf(0.5f * l);
  }
}

// ===========================================================================
extern "C" void kernel_launch(void* const* d_in, const int* in_sizes, int n_in,
                              void* d_out, int out_size, void* d_ws, size_t ws_size,
                              hipStream_t stream)
{
  const float* x       = (const float*)d_in[0];
  const float* input_w = (const float*)d_in[1];
  const float* input_b = (const float*)d_in[2];
  const float* dil_w   = (const float*)d_in[3];
  const float* dil_b   = (const float*)d_in[4];
  const float* gate_w  = (const float*)d_in[5];
  const float* gate_b  = (const float*)d_in[6];
  const float* skip_w  = (const float*)d_in[7];
  const float* skip_b  = (const float*)d_in[8];
  const float* res_w   = (const float*)d_in[9];
  const float* res_b   = (const float*)d_in[10];
  const float* e1w     = (const float*)d_in[11];
  const float* e1b     = (const float*)d_in[12];
  const float* mw      = (const float*)d_in[13];
  const float* mb      = (const float*)d_in[14];
  const float* lw      = (const float*)d_in[15];
  const float* lb      = (const float*)d_in[16];
  float* out = (float*)d_out;

  // shared workspace layout (coop's Hg overlaps fallback's hA; one path per call)
  float* ws        = (float*)d_ws;
  float* hA        = ws;
  float* hB        = hA + HSZ;
  float* skip_last = hB + HSZ;
  unsigned short* W1bf = (unsigned short*)(skip_last + BATCH * 64);
  unsigned short* Wrbf = W1bf + (size_t)NLAYERS * 128 * 128;
  unsigned short* Hg   = (unsigned short*)d_ws;

  // ---- guarded cooperative attempt (host queries only; capture-safe) ----
  int dev = 0;
  (void)hipGetDevice(&dev);
  int coopAttr = 0;
  (void)hipDeviceGetAttribute(&coopAttr, hipDeviceAttributeCooperativeLaunch, dev);
  int nCU = 0;
  (void)hipDeviceGetAttribute(&nCU, hipDeviceAttributeMultiprocessorCount, dev);
  int maxBlk = 0;
  (void)hipOccupancyMaxActiveBlocksPerMultiprocessor(&maxBlk, wavenet_mega, 256,
                                                     (size_t)65536);
  hipError_t cerr = hipErrorUnknown;
  if (coopAttr && maxBlk > 0 && (long)maxBlk * nCU >= NT * BATCH) {
    void* args[] = {
      (void*)&x, (void*)&input_w, (void*)&input_b,
      (void*)&dil_w, (void*)&dil_b, (void*)&gate_w, (void*)&gate_b,
      (void*)&skip_w, (void*)&skip_b, (void*)&res_w, (void*)&res_b,
      (void*)&e1w, (void*)&e1b, (void*)&mw, (void*)&mb, (void*)&lw, (void*)&lb,
      (void*)&Hg, (void*)&skip_last, (void*)&W1bf, (void*)&Wrbf, (void*)&out
    };
    cerr = hipLaunchCooperativeKernel((void*)wavenet_mega, dim3(NT, BATCH),
                                      dim3(256), args, 65536, stream);
  }
  if (cerr == hipSuccess) return;

  // ---- fallback: proven round-2 sequence ----
  int dil[NLAYERS];
  int R[NLAYERS + 1];
  for (int blk = 0; blk < 3; ++blk)
    for (int l = 0; l < 10; ++l) dil[blk * 10 + l] = 1 << l;
  R[NLAYERS] = L_SEQ;
  for (int i = NLAYERS - 1; i >= 0; --i) R[i] = R[i + 1] - dil[i];

  prep_kernel<<<(NLAYERS * 128 * 128 + 255) / 256, 256, 0, stream>>>(
      dil_w, gate_w, res_w, W1bf, Wrbf, skip_last);

  {
    int nt = L_SEQ - R[0];  // 3069
    dim3 g((nt + 255) / 256, BATCH);
    input_conv_kernel<<<g, 256, 0, stream>>>(x, input_w, input_b, hA);
  }

  float* hin  = hA;
  float* hout = hB;
  for (int i = 0; i < NLAYERS; ++i) {
    int nt = L_SEQ - R[i + 1];
    dim3 g((nt + 63) / 64 + 1, BATCH);
    layer_kernel<<<g, 256, 65536, stream>>>(
        hin, hout, W1bf, Wrbf,
        dil_w, gate_w, skip_w,
        dil_b, gate_b, res_b, skip_b,
        skip_last, i, dil[i], R[i + 1]);
    float* tmp = hin; hin = hout; hout = tmp;
  }

  final_kernel<<<1, 256, 0, stream>>>(skip_last, e1w, e1b, mw, mb, lw, lb, out);
}

// Round 7
// 766.415 us; speedup vs baseline: 1.1604x; 1.0334x over previous
//
#include <hip/hip_runtime.h>
#include <hip/hip_bf16.h>
#include <cstddef>

#define L_SEQ   4096
#define BATCH   32
#define TOFF    1024
#define TBUF    3072
#define NLAYERS 30

typedef __attribute__((ext_vector_type(8))) short short8v;
typedef __attribute__((ext_vector_type(4))) float f32x4;

static const size_t HSZ = (size_t)BATCH * TBUF * 64;

// layer-kernel LDS (65536 B dynamic, 2 blocks/CU):
//   A:  128 rows x 128k bf16, stride 256B, swizzled  [0, 32768)
//       (z overlays bytes [0,128) of each wave's own A rows after GEMM1)
//   W1: 128 rows x 128k bf16, stride 256B, swizzled  [32768, 65536)
#define L_A  0
#define L_B  32768

__device__ inline float fast_sigmoid(float x) {
  x = fminf(fmaxf(x, -30.f), 30.f);
  return __builtin_amdgcn_rcpf(1.f + __expf(-x));
}
__device__ inline float fast_tanh(float x) {
  x = fminf(fmaxf(x, -15.f), 15.f);
  float e = __expf(-2.f * x);
  return (1.f - e) * __builtin_amdgcn_rcpf(1.f + e);
}
__device__ inline unsigned short f2bf(float f) {  // RNE fp32 -> bf16
  unsigned u = __float_as_uint(f);
  unsigned r = u + 0x7FFF + ((u >> 16) & 1);
  return (unsigned short)(r >> 16);
}
__device__ inline short8v lds_frag(const char* smem, int base, int row, int kk,
                                   int rowstride) {
  int byte = base + row * rowstride + kk * 2;
  byte ^= (row & 7) << 4;
  return *(const short8v*)(smem + byte);
}

// ---------------------------------------------------------------------------
__global__ __launch_bounds__(256) void prep_kernel(
    const float* __restrict__ dil_w, const float* __restrict__ gate_w,
    const float* __restrict__ res_w,
    unsigned short* __restrict__ W1bf, unsigned short* __restrict__ Wrbf,
    float* __restrict__ skip_last)
{
  int idx = blockIdx.x * 256 + threadIdx.x;
  if (idx < NLAYERS * 128 * 128) {
    int l = idx >> 14, r = idx & 16383, n = r >> 7, k = r & 127;
    const float* src = (n < 64) ? dil_w : gate_w;
    int oc = n & 63;
    float v = src[(((size_t)l * 64 + oc) * 64 + (k & 63)) * 2 + (k >> 6)];
    W1bf[idx] = f2bf(v);
  }
  if (idx < NLAYERS * 64 * 64) Wrbf[idx] = f2bf(res_w[idx]);
  if (idx < BATCH * 64) skip_last[idx] = 0.f;
}

// ---------------------------------------------------------------------------
// input 1x1 conv (fp32): register-accumulated, burst float4 stores
// ---------------------------------------------------------------------------
__global__ __launch_bounds__(256) void input_conv_kernel(
    const float* __restrict__ x, const float* __restrict__ w,
    const float* __restrict__ bias, float* __restrict__ h)
{
  int b = blockIdx.y;
  int t = 1027 + blockIdx.x * 256 + threadIdx.x;
  if (t >= L_SEQ) return;
  const float* xp = x + ((size_t)b * L_SEQ + t) * 32;
  float xin[32];
#pragma unroll
  for (int j = 0; j < 8; ++j) {
    float4 v = ((const float4*)xp)[j];
    xin[4*j+0] = v.x; xin[4*j+1] = v.y; xin[4*j+2] = v.z; xin[4*j+3] = v.w;
  }
  float* hp = h + ((size_t)b * TBUF + (t - TOFF)) * 64;
#pragma unroll
  for (int half = 0; half < 2; ++half) {
    float acc[32];
#pragma unroll 2
    for (int o = 0; o < 32; ++o) {
      int oc = half * 32 + o;
      float a0 = bias[oc], a1 = 0.f;
#pragma unroll
      for (int k = 0; k < 32; k += 2) {
        a0 += w[oc * 32 + k]     * xin[k];
        a1 += w[oc * 32 + k + 1] * xin[k + 1];
      }
      acc[o] = a0 + a1;
    }
#pragma unroll
    for (int q = 0; q < 8; ++q)
      ((float4*)hp)[half * 8 + q] =
          make_float4(acc[4*q+0], acc[4*q+1], acc[4*q+2], acc[4*q+3]);
  }
}

// ---------------------------------------------------------------------------
// fused MFMA layer: block = 128 positions x 1 batch, 8 waves (16 pos/wave).
// One barrier per block. z overlays each wave's own A rows (wave-private).
// tail block: skip tap at virtual t = L (VALU)
// ---------------------------------------------------------------------------
__global__ __launch_bounds__(512, 4) void layer_kernel(
    const float* __restrict__ hin, float* __restrict__ hout,
    const unsigned short* __restrict__ W1bf, const unsigned short* __restrict__ Wrbf,
    const float* __restrict__ dil_w, const float* __restrict__ gate_w,
    const float* __restrict__ skip_w,
    const float* __restrict__ dil_b, const float* __restrict__ gate_b,
    const float* __restrict__ res_b, const float* __restrict__ skip_b,
    float* __restrict__ skip_last, int layer, int d, int tstart)
{
  extern __shared__ char smem[];
  const int b = blockIdx.y;
  const int tid = threadIdx.x;

  if (blockIdx.x == gridDim.x - 1) {
    // ---- skip tail at t = L: z uses only tap0 at h[L-d] ----
    float* hp = (float*)smem;
    float* zl = hp + 64;
    if (tid < 64)
      hp[tid] = hin[((size_t)b * TBUF + (L_SEQ - d - TOFF)) * 64 + tid];
    __syncthreads();
    if (tid < 64) {
      int dc = tid;
      float f = dil_b[layer * 64 + dc], gg = gate_b[layer * 64 + dc];
      const float* wd = dil_w  + (size_t)(layer * 64 + dc) * 128;
      const float* wg = gate_w + (size_t)(layer * 64 + dc) * 128;
      for (int ic = 0; ic < 64; ++ic) {
        f  += wd[ic * 2] * hp[ic];
        gg += wg[ic * 2] * hp[ic];
      }
      zl[dc] = fast_tanh(f) * fast_sigmoid(gg);
    }
    __syncthreads();
    if (tid < 64) {
      int co = tid;
      float s = skip_b[layer * 64 + co];
      const float* wsk = skip_w + (size_t)(layer * 64 + co) * 64;
      for (int dc = 0; dc < 64; ++dc) s += wsk[dc] * zl[dc];
      skip_last[b * 64 + co] += s;   // race-free: launches serialize layers
    }
    return;
  }

  const int t0 = tstart + blockIdx.x * 128;

  // ---- stage A: 128 rows x 128k bf16 (hprev | hcur), swizzled ----
  {
    int row = tid >> 2, part = tid & 3;
    int t = t0 + row; if (t >= L_SEQ) t = L_SEQ - 1;   // clamp; masked at write
    int tsrc = (part < 2) ? (t - d) : t;
    const float* src = hin + ((size_t)b * TBUF + (tsrc - TOFF)) * 64 + (part & 1) * 32;
    float v[32];
#pragma unroll
    for (int q = 0; q < 8; ++q) {
      float4 f4 = ((const float4*)src)[q];
      v[4*q] = f4.x; v[4*q+1] = f4.y; v[4*q+2] = f4.z; v[4*q+3] = f4.w;
    }
#pragma unroll
    for (int c = 0; c < 4; ++c) {
      short8v pk;
#pragma unroll
      for (int e = 0; e < 8; ++e) pk[e] = (short)f2bf(v[c * 8 + e]);
      int byte = (row * 256 + part * 64 + c * 16) ^ ((row & 7) << 4);
      *(short8v*)(smem + L_A + byte) = pk;
    }
  }
  // ---- stage W1: 128 rows x 128k bf16, swizzled ----
  {
    int n = tid >> 2, q = tid & 3;
    const short8v* src =
        (const short8v*)(W1bf + (size_t)layer * 16384 + n * 128 + q * 32);
#pragma unroll
    for (int c = 0; c < 4; ++c) {
      short8v pk = src[c];
      int byte = (n * 256 + q * 64 + c * 16) ^ ((n & 7) << 4);
      *(short8v*)(smem + L_B + byte) = pk;
    }
  }
  __syncthreads();   // the only barrier

  const int lane = tid & 63;
  const int wv   = tid >> 6;
  const int r0   = wv * 16;         // wave's 16 position-rows
  const int lcol = lane & 15;
  const int lg   = lane >> 4;

  // ---- GEMM1: C[pos][n=f|g], bias pre-seeded ----
  short8v a[4];
#pragma unroll
  for (int s = 0; s < 4; ++s)
    a[s] = lds_frag(smem, L_A, r0 + lcol, s * 32 + lg * 8, 256);
  f32x4 cf[8];
#pragma unroll
  for (int j = 0; j < 8; ++j) {
    int n = j * 16 + lcol;
    float bias = (n < 64) ? dil_b[layer * 64 + n] : gate_b[layer * 64 + n - 64];
    cf[j] = (f32x4){bias, bias, bias, bias};
  }
#pragma unroll
  for (int s = 0; s < 4; ++s) {
#pragma unroll
    for (int j = 0; j < 8; ++j) {
      short8v bb = lds_frag(smem, L_B, j * 16 + lcol, s * 32 + lg * 8, 256);
      cf[j] = __builtin_amdgcn_mfma_f32_16x16x32_bf16(a[s], bb, cf[j], 0, 0, 0);
    }
  }

  // ---- activation -> z overlays wave's own A rows (bytes [0,128) per row) ----
#pragma unroll
  for (int j = 0; j < 4; ++j) {
#pragma unroll
    for (int r = 0; r < 4; ++r) {
      float z = fast_tanh(cf[j][r]) * fast_sigmoid(cf[j + 4][r]);
      int row = r0 + lg * 4 + r;          // C layout: row=(lane>>4)*4+reg
      int byte = (row * 256 + (j * 16 + lcol) * 2) ^ ((row & 7) << 4);
      *(unsigned short*)(smem + L_A + byte) = f2bf(z);
    }
  }

  // ---- Wr fragments in registers (global, L2-hot) ----
  short8v wr[4][2];
  const unsigned short* wrp = Wrbf + (size_t)layer * 4096;
#pragma unroll
  for (int j2 = 0; j2 < 4; ++j2)
#pragma unroll
    for (int s2 = 0; s2 < 2; ++s2)
      wr[j2][s2] = *(const short8v*)(wrp + (j2 * 16 + lcol) * 64 + s2 * 32 + lg * 8);

  // ---- GEMM2 + fp32 residual epilogue ----
  f32x4 c2[4];
#pragma unroll
  for (int j2 = 0; j2 < 4; ++j2) {
    float bias = res_b[layer * 64 + j2 * 16 + lcol];
    c2[j2] = (f32x4){bias, bias, bias, bias};
  }
#pragma unroll
  for (int s2 = 0; s2 < 2; ++s2) {
    short8v a2 = lds_frag(smem, L_A, r0 + lcol, s2 * 32 + lg * 8, 256);
#pragma unroll
    for (int j2 = 0; j2 < 4; ++j2)
      c2[j2] = __builtin_amdgcn_mfma_f32_16x16x32_bf16(a2, wr[j2][s2], c2[j2], 0, 0, 0);
  }
#pragma unroll
  for (int j2 = 0; j2 < 4; ++j2) {
    int col = j2 * 16 + lcol;
#pragma unroll
    for (int r = 0; r < 4; ++r) {
      int t = t0 + r0 + lg * 4 + r;
      if (t < L_SEQ) {
        size_t idx = ((size_t)b * TBUF + t - TOFF) * 64 + col;
        hout[idx] = hin[idx] + c2[j2][r];
      }
    }
  }
}

// ---------------------------------------------------------------------------
// epilogue head: relu -> end1 (64->128) -> relu -> mean/lv -> vol
// ---------------------------------------------------------------------------
__global__ __launch_bounds__(256) void final_kernel(
    const float* __restrict__ skip_last,
    const float* __restrict__ e1w, const float* __restrict__ e1b,
    const float* __restrict__ mw,  const float* __restrict__ mb,
    const float* __restrict__ lw,  const float* __restrict__ lb,
    float* __restrict__ out)
{
  __shared__ float rm[8][32], rl[8][32];
  int b  = threadIdx.x & 31;
  int eg = threadIdx.x >> 5;
  float y1[64];
  const float4* yp = (const float4*)(skip_last + b * 64);
#pragma unroll
  for (int q = 0; q < 16; ++q) {
    float4 v = yp[q];
    y1[4*q+0] = fmaxf(v.x, 0.f); y1[4*q+1] = fmaxf(v.y, 0.f);
    y1[4*q+2] = fmaxf(v.z, 0.f); y1[4*q+3] = fmaxf(v.w, 0.f);
  }
  float mp = 0.f, lp = 0.f;
  for (int ei = 0; ei < 16; ++ei) {
    int e = eg * 16 + ei;
    const float4* wp = (const float4*)(e1w + e * 64);
    float a0 = e1b[e], a1 = 0.f;
#pragma unroll
    for (int q = 0; q < 16; ++q) {
      float4 w4 = wp[q];
      a0 += w4.x * y1[4*q+0] + w4.z * y1[4*q+2];
      a1 += w4.y * y1[4*q+1] + w4.w * y1[4*q+3];
    }
    float a = fmaxf(a0 + a1, 0.f);
    mp += mw[e] * a;
    lp += lw[e] * a;
  }
  rm[eg][b] = mp; rl[eg][b] = lp;
  __syncthreads();
  if (threadIdx.x < 32) {
    int bb = threadIdx.x;
    float m = mb[0], l = lb[0];
#pragma unroll
    for (int g = 0; g < 8; ++g) { m += rm[g][bb]; l += rl[g][bb]; }
    out[bb]      = m;
    out[32 + bb] = l;
    out[64 + bb] = expf(0.5f * l);
  }
}

// ---------------------------------------------------------------------------
extern "C" void kernel_launch(void* const* d_in, const int* in_sizes, int n_in,
                              void* d_out, int out_size, void* d_ws, size_t ws_size,
                              hipStream_t stream)
{
  const float* x       = (const float*)d_in[0];
  const float* input_w = (const float*)d_in[1];
  const float* input_b = (const float*)d_in[2];
  const float* dil_w   = (const float*)d_in[3];
  const float* dil_b   = (const float*)d_in[4];
  const float* gate_w  = (const float*)d_in[5];
  const float* gate_b  = (const float*)d_in[6];
  const float* skip_w  = (const float*)d_in[7];
  const float* skip_b  = (const float*)d_in[8];
  const float* res_w   = (const float*)d_in[9];
  const float* res_b   = (const float*)d_in[10];
  const float* e1w     = (const float*)d_in[11];
  const float* e1b     = (const float*)d_in[12];
  const float* mw      = (const float*)d_in[13];
  const float* mb      = (const float*)d_in[14];
  const float* lw      = (const float*)d_in[15];
  const float* lb      = (const float*)d_in[16];
  float* out = (float*)d_out;

  float* ws        = (float*)d_ws;
  float* hA        = ws;
  float* hB        = hA + HSZ;
  float* skip_last = hB + HSZ;
  unsigned short* W1bf = (unsigned short*)(skip_last + BATCH * 64);
  unsigned short* Wrbf = W1bf + (size_t)NLAYERS * 128 * 128;

  int dil[NLAYERS];
  int R[NLAYERS + 1];
  for (int blk = 0; blk < 3; ++blk)
    for (int l = 0; l < 10; ++l) dil[blk * 10 + l] = 1 << l;
  R[NLAYERS] = L_SEQ;
  for (int i = NLAYERS - 1; i >= 0; --i) R[i] = R[i + 1] - dil[i];
  // R[0] == 1027

  prep_kernel<<<(NLAYERS * 128 * 128 + 255) / 256, 256, 0, stream>>>(
      dil_w, gate_w, res_w, W1bf, Wrbf, skip_last);

  {
    int nt = L_SEQ - R[0];  // 3069
    dim3 g((nt + 255) / 256, BATCH);
    input_conv_kernel<<<g, 256, 0, stream>>>(x, input_w, input_b, hA);
  }

  float* hin  = hA;
  float* hout = hB;
  for (int i = 0; i < NLAYERS; ++i) {
    int nt = L_SEQ - R[i + 1];            // normal positions (0 for last layer)
    dim3 g((nt + 127) / 128 + 1, BATCH);  // +1 tail block for skip @ t=L
    layer_kernel<<<g, 512, 65536, stream>>>(
        hin, hout, W1bf, Wrbf,
        dil_w, gate_w, skip_w,
        dil_b, gate_b, res_b, skip_b,
        skip_last, i, dil[i], R[i + 1]);
    float* tmp = hin; hin = hout; hout = tmp;
  }

  final_kernel<<<1, 256, 0, stream>>>(skip_last, e1w, e1b, mw, mb, lw, lb, out);
}